// Round 10
// baseline (277.027 us; speedup 1.0000x reference)
//
#include <hip/hip_runtime.h>
#include <math.h>

#define DIM 768
#define HEADS 12
#define DH 64
#define NSEQ 4096
#define BATCH 2
#define BH (BATCH * HEADS)

typedef __attribute__((ext_vector_type(8))) short bf16x8;
typedef __attribute__((ext_vector_type(4))) float f32x4;

typedef const __attribute__((address_space(1))) unsigned char* as1_u8;
typedef __attribute__((address_space(3))) unsigned char* as3_u8;

// round-half-up bf16: <=0.5 ULP, 2 VALU ops
__device__ __forceinline__ unsigned short f2bf(float x) {
  return (unsigned short)((__float_as_uint(x) + 0x8000u) >> 16);
}

// raw v_exp_f32 = 2^x. s_nop 0 covers the trans->VALU 1-wait-state hazard.
__device__ __forceinline__ float exp2_fast(float x) {
  float r;
  asm volatile("v_exp_f32 %0, %1\n\ts_nop 0" : "=v"(r) : "v"(x));
  return r;
}

// async global->LDS DMA, 16B per lane; LDS dest = wave-uniform base + lane*16
__device__ __forceinline__ void gl16(const void* g, void* l) {
  __builtin_amdgcn_global_load_lds((as1_u8)g, (as3_u8)l, 16, 0, 0);
}

// ---------------------------------------------------------------------------
// fp32 -> bf16 elementwise (x). 8 elems/thread. 38 MB traffic (~8 us).
// ---------------------------------------------------------------------------
__global__ __launch_bounds__(256) void cvt_bf16(const float* __restrict__ in,
                                                unsigned short* __restrict__ out,
                                                int n) {
  int i = (blockIdx.x * 256 + threadIdx.x) * 8;
  if (i >= n) return;
  float4 a = *(const float4*)(in + i);
  float4 b = *(const float4*)(in + i + 4);
  ushort4 v0, v1;
  v0.x = f2bf(a.x); v0.y = f2bf(a.y); v0.z = f2bf(a.z); v0.w = f2bf(a.w);
  v1.x = f2bf(b.x); v1.y = f2bf(b.y); v1.z = f2bf(b.z); v1.w = f2bf(b.w);
  *(ushort4*)(out + i) = v0;
  *(ushort4*)(out + i + 4) = v1;
}

// ---------------------------------------------------------------------------
// Merged weight transpose+convert: both w_qkv [768][2304] and w_out [768][768]
// fp32 -> [N][768] bf16 in ONE launch (grid.x 0..71 -> qkv, 72..95 -> out).
// ---------------------------------------------------------------------------
__global__ __launch_bounds__(256) void transpose_cvt2(
    const float* __restrict__ wqkv, unsigned short* __restrict__ wqkvT,
    const float* __restrict__ wout, unsigned short* __restrict__ woutT) {
  __shared__ unsigned short s[32][34];
  int t = threadIdx.x;
  int tx = t & 31, ty = t >> 5;
  int bx = blockIdx.x;
  const float* in;
  unsigned short* out;
  int N, n0;
  if (bx < 72) { in = wqkv; out = wqkvT; N = 3 * DIM; n0 = bx * 32; }
  else         { in = wout; out = woutT; N = DIM;     n0 = (bx - 72) * 32; }
  int k0 = blockIdx.y * 32;
#pragma unroll
  for (int i = 0; i < 4; ++i) {
    int r = ty + i * 8;
    s[r][tx] = f2bf(in[(size_t)(k0 + r) * N + n0 + tx]);
  }
  __syncthreads();
#pragma unroll
  for (int i = 0; i < 4; ++i) {
    int r = ty + i * 8;
    out[(size_t)(n0 + r) * DIM + k0 + tx] = s[tx][r];
  }
}

// ---------------------------------------------------------------------------
// bf16 MFMA GEMM v8: C[M,N] = A[M,K] @ Bt[N,K]^T + bias.
// Double-buffered K-loop (attn-style): {vmcnt(0); barrier; issue next-tile
// DMA into buf^1; MFMA on buf}. One barrier per K-step. TM=64,
// LDS 2x24KB=48KB -> 3 blocks/CU. global_load_lds 16B DMA, content
// XOR-chunk-swizzled via pre-swizzled global source; XCD-aware block swizzle.
// mode 0 (QKV): -> Qb(scaled)/Kb bf16 rows; V blocks (which==2,
// block-uniform) are read back TRANSPOSED from the C-scratch and written
// straight to Vt [bh][dh][n] (vtrans kernel fused away).
// mode 1: fp32 out rows, full-line stores.
// ---------------------------------------------------------------------------
template <int TM>
__global__ __launch_bounds__(256, 3) void gemm_bt(
    const unsigned short* __restrict__ Ab, const unsigned short* __restrict__ Bt,
    const float* __restrict__ bias, float* __restrict__ outf,
    unsigned short* __restrict__ Qb, unsigned short* __restrict__ Kb,
    unsigned short* __restrict__ Vt, int M, int N, int K, int mode) {
  constexpr int ABYTES = TM * 128;   // per-buffer A bytes
  constexpr int BBYTES = 128 * 128;  // per-buffer B bytes
  __shared__ __align__(16) char Sraw[2 * (ABYTES + BBYTES)];
  constexpr int MI = TM / 32;
  const int t = threadIdx.x;
  const int wave = t >> 6, lane = t & 63;
  const int ln16 = lane & 15, quad = lane >> 4;
  const int sw = ln16 & 7;

  // XCD-aware swizzle: each XCD gets a contiguous chunk of work ids.
  const int nbx = gridDim.x;
  const int nwg = nbx * gridDim.y;
  int bid = blockIdx.x + blockIdx.y * nbx;
  int nbid = (bid & 7) * (nwg >> 3) + (bid >> 3);  // nwg % 8 == 0 for both gemms
  const int cb = nbid % nbx, rb = nbid / nbx;

  const int rw = (wave >> 1) * (TM / 2);
  const int cw = (wave & 1) * 64;

  // DMA geometry: one gl16 covers 8 rows x 128B. row8=lane>>3, chunk lane&7.
  // Source chunk pre-swizzled so LDS[row][c] = true[row][c ^ (row&7)].
  const int row8 = lane >> 3;
  const int csw = (lane & 7) ^ row8;

  f32x4 acc[MI][4];
#pragma unroll
  for (int i = 0; i < MI; ++i)
#pragma unroll
    for (int j = 0; j < 4; ++j) acc[i][j] = (f32x4){0.f, 0.f, 0.f, 0.f};

  const unsigned short* gA = Ab + (size_t)(rb * TM + row8) * K + csw * 8;
  const unsigned short* gB = Bt + (size_t)(cb * 128 + row8) * K + csw * 8;

  auto stage = [&](int b, int k0) {
    char* base = Sraw + b * (ABYTES + BBYTES);
    unsigned short* As = (unsigned short*)base;
    unsigned short* Bs = (unsigned short*)(base + ABYTES);
#pragma unroll
    for (int i = 0; i < MI; ++i) {
      int rr = wave * (TM / 4) + i * 8;
      gl16(gA + (size_t)rr * K + k0, &As[rr * 64]);
    }
#pragma unroll
    for (int i = 0; i < 4; ++i) {
      int rr = wave * 32 + i * 8;
      gl16(gB + (size_t)rr * K + k0, &Bs[rr * 64]);
    }
  };

  stage(0, 0);
  int buf = 0;

  for (int k0 = 0; k0 < K; k0 += 64) {
    asm volatile("s_waitcnt vmcnt(0)" ::: "memory");  // own DMA for buf done
    __syncthreads();  // all waves' DMA done; prev tile (buf^1) fully consumed
    if (k0 + 64 < K) stage(buf ^ 1, k0 + 64);  // prefetch rides this compute

    const unsigned short* Asb =
        (const unsigned short*)(Sraw + buf * (ABYTES + BBYTES));
    const unsigned short* Bs =
        (const unsigned short*)(Sraw + buf * (ABYTES + BBYTES) + ABYTES);
#pragma unroll
    for (int kh = 0; kh < 2; ++kh) {
      bf16x8 a[MI], b[4];
#pragma unroll
      for (int mi = 0; mi < MI; ++mi) {
        int row = rw + mi * 16 + ln16;
        a[mi] = *(const bf16x8*)&Asb[row * 64 + (((kh << 2) | quad) ^ sw) * 8];
      }
#pragma unroll
      for (int ni = 0; ni < 4; ++ni) {
        int row = cw + ni * 16 + ln16;
        b[ni] = *(const bf16x8*)&Bs[row * 64 + (((kh << 2) | quad) ^ sw) * 8];
      }
#pragma unroll
      for (int mi = 0; mi < MI; ++mi)
#pragma unroll
        for (int ni = 0; ni < 4; ++ni)
          acc[mi][ni] = __builtin_amdgcn_mfma_f32_16x16x32_bf16(a[mi], b[ni],
                                                                acc[mi][ni], 0, 0, 0);
    }
    buf ^= 1;
  }

  // epilogue lane mapping for full-line stores
  const int erow = lane >> 3;        // 0..7 (row within 8-row group)
  const int ecol = (lane & 7) * 8;   // elem col (8 elems = 16B bf16 / 32B fp32)

  if (mode == 0) {
    __syncthreads();  // all waves done with LDS tiles; reuse as fp32 C-scratch
    // 768^-0.5 * log2(e): attention uses raw v_exp_f32 (2^x), so the log2e
    // factor is folded into the Q scale here. exp2(S*log2e) == exp(S).
    const float scale = 0.0520587731f;
    int col0abs = cb * 128 + cw;                 // multiple of 64
    int which = (col0abs >= 2 * DIM) ? 2 : ((col0abs >= DIM) ? 1 : 0);
    int h = (col0abs - which * DIM) >> 6;        // wave covers one full head
    const float mul = (which == 0) ? scale : 1.f;
    float* Cs = (float*)Sraw + wave * (16 * 68);  // 16 rows x 68 floats per wave
    float bvv[4];
#pragma unroll
    for (int ni = 0; ni < 4; ++ni) bvv[ni] = bias[col0abs + ni * 16 + ln16];
    int bb = (rb * TM) >> 12;  // batch index, uniform over the block's tokens
    size_t planebase = (size_t)(bb * HEADS + h) * NSEQ;

    if (which == 2) {
      // V: read scratch TRANSPOSED (lane = dh), store to Vt[bh][dh][n]
      // in 16-token 32B runs. Fuses the old vtrans kernel away.
#pragma unroll
      for (int mi = 0; mi < MI; ++mi) {
#pragma unroll
        for (int ni = 0; ni < 4; ++ni)
#pragma unroll
          for (int r = 0; r < 4; ++r)
            Cs[(quad * 4 + r) * 68 + ni * 16 + ln16] = acc[mi][ni][r] + bvv[ni];
        __asm__ volatile("s_waitcnt lgkmcnt(0)" ::: "memory");  // wave-local
        int n0 = (rb * TM + rw + mi * 16) & (NSEQ - 1);
        unsigned short tmp[16];
#pragma unroll
        for (int r = 0; r < 16; ++r) tmp[r] = f2bf(Cs[r * 68 + lane]);
        unsigned short* dp =
            Vt + ((size_t)((bb * HEADS + h) * DH + lane)) * NSEQ + n0;
        *(uint4*)&dp[0] = *(uint4*)&tmp[0];
        *(uint4*)&dp[8] = *(uint4*)&tmp[8];
        __asm__ volatile("s_waitcnt lgkmcnt(0)" ::: "memory");
      }
    } else {
      unsigned short* dstp = (which == 0) ? Qb : Kb;
#pragma unroll
      for (int mi = 0; mi < MI; ++mi) {
#pragma unroll
        for (int ni = 0; ni < 4; ++ni)
#pragma unroll
          for (int r = 0; r < 4; ++r)
            Cs[(quad * 4 + r) * 68 + ni * 16 + ln16] = (acc[mi][ni][r] + bvv[ni]) * mul;
        __asm__ volatile("s_waitcnt lgkmcnt(0)" ::: "memory");  // wave-local
#pragma unroll
        for (int i2 = 0; i2 < 2; ++i2) {
          int rloc = i2 * 8 + erow;
          const float* src = &Cs[rloc * 68 + ecol];
          float4 c0 = *(const float4*)(src + 0);
          float4 c1 = *(const float4*)(src + 4);
          unsigned short tmp[8];
          tmp[0] = f2bf(c0.x); tmp[1] = f2bf(c0.y); tmp[2] = f2bf(c0.z); tmp[3] = f2bf(c0.w);
          tmp[4] = f2bf(c1.x); tmp[5] = f2bf(c1.y); tmp[6] = f2bf(c1.z); tmp[7] = f2bf(c1.w);
          int nn = (rb * TM + rw + mi * 16 + rloc) & (NSEQ - 1);
          // lanes: 8 consecutive rows x 128B contiguous -> 8 full lines/store
          *(uint4*)&dstp[(planebase + nn) * DH + ecol] = *(uint4*)tmp;
        }
        __asm__ volatile("s_waitcnt lgkmcnt(0)" ::: "memory");  // reads done
      }
    }
  } else {
    // mode 1: fp32 out via LDS scratch, full-line stores (each instruction:
    // 8 rows x 128B-contiguous aligned pieces).
    __syncthreads();
    float* Cs = (float*)Sraw + wave * (16 * 68);
    float bvv[4];
#pragma unroll
    for (int ni = 0; ni < 4; ++ni) bvv[ni] = bias[cb * 128 + cw + ni * 16 + ln16];
    const int fcol = (lane & 7) * 4;  // float col within 64, 16B chunks
#pragma unroll
    for (int mi = 0; mi < MI; ++mi) {
#pragma unroll
      for (int ni = 0; ni < 4; ++ni)
#pragma unroll
        for (int r = 0; r < 4; ++r)
          Cs[(quad * 4 + r) * 68 + ni * 16 + ln16] = acc[mi][ni][r] + bvv[ni];
      __asm__ volatile("s_waitcnt lgkmcnt(0)" ::: "memory");  // wave-local
#pragma unroll
      for (int i2 = 0; i2 < 2; ++i2) {
#pragma unroll
        for (int s = 0; s < 2; ++s) {
          int rloc = i2 * 8 + erow;
          int cloc = fcol + s * 32;
          float4 c = *(const float4*)&Cs[rloc * 68 + cloc];
          int token = rb * TM + rw + mi * 16 + rloc;
          *(float4*)(outf + (size_t)token * N + cb * 128 + cw + cloc) = c;
        }
      }
      __asm__ volatile("s_waitcnt lgkmcnt(0)" ::: "memory");
    }
  }
}

// ---------------------------------------------------------------------------
// MFMA flash attention v6: QBLK=64 (was 128) -> grid 1536 blocks = 5 resident
// blocks/CU (LDS 5x32KB = 160KB exact) = 5 waves/SIMD (was 3). Per-wave state
// halved (16 q-rows, mi-loop gone: 18 MFMA, 16 exp2, 8 cvt_pk, 8 permlane
// per tile). Total MFMA work unchanged; K/V staging traffic 2x (L2-served,
// ~13.5 TB/s << 34.5 ceiling). Same swapped-QK^T / in-register P exchange /
// gl16 dbuf / ones-column denominator / XCD swizzle as v4.
// ---------------------------------------------------------------------------
__global__ __launch_bounds__(256, 5) void attn_mfma6(
    const unsigned short* __restrict__ Qg, const unsigned short* __restrict__ Kg,
    const unsigned short* __restrict__ Vtg, unsigned short* __restrict__ ctxb) {
  __shared__ unsigned short Ks[2][64][64];   // [buf][key][dh], chunk-XOR-swizzled
  __shared__ unsigned short Vts[2][64][64];  // [buf][dh][key], chunk-XOR-swizzled

  const int t = threadIdx.x;
  const int wave = t >> 6, lane = t & 63;
  const int ln16 = lane & 15, quad = lane >> 4;

  // XCD swizzle: nwg = 64*24 = 1536, 192 per XCD = 3 heads x 64 q-blocks.
  int bid = blockIdx.x + blockIdx.y * 64;
  int nbid = (bid & 7) * 192 + (bid >> 3);
  const int bh = nbid >> 6;
  const int q0 = (nbid & 63) * 64;

  // Q fragments (registers, whole kernel): wave covers 16 q-rows.
  const unsigned short* Qp = Qg + ((size_t)bh * NSEQ + q0 + wave * 16) * DH;
  bf16x8 qf[2];
#pragma unroll
  for (int kh = 0; kh < 2; ++kh)
    qf[kh] = *(const bf16x8*)(Qp + (size_t)ln16 * DH + kh * 32 + quad * 8);

  f32x4 O[5];
#pragma unroll
  for (int nt = 0; nt < 5; ++nt) O[nt] = (f32x4){0.f, 0.f, 0.f, 0.f};

  const unsigned short* Kbase = Kg + (size_t)bh * NSEQ * DH;
  const unsigned short* Vbase = Vtg + (size_t)bh * DH * NSEQ;

  // staging geometry: per gl16 a wave covers 8 rows x 128B; row = lane>>3,
  // chunk = lane&7. Source chunk pre-swizzled by row&7 so that
  // LDS[row][c] = true[row][c ^ (row&7)] (16B-chunk XOR swizzle).
  const int row8 = lane >> 3;
  const int csw = (lane & 7) ^ row8;

  auto stage = [&](int b, int kk) {
#pragma unroll
    for (int i = 0; i < 2; ++i) {
      int rr = wave * 16 + i * 8;
      gl16(Kbase + (size_t)(kk + rr + row8) * DH + csw * 8, &Ks[b][rr][0]);
      gl16(Vbase + (size_t)(rr + row8) * NSEQ + kk + csw * 8, &Vts[b][rr][0]);
    }
  };

  // ones B-fragment for denominator column (row 0 of B = ones)
  union { unsigned int u[4]; bf16x8 v; } VO;
  {
    unsigned int ow = (ln16 == 0) ? 0x3F803F80u : 0u;
    VO.u[0] = ow; VO.u[1] = ow; VO.u[2] = ow; VO.u[3] = ow;
  }
  const bf16x8 vone = VO.v;

  stage(0, 0);
  const int sw = ln16 & 7;
  int buf = 0;

  for (int k0 = 0; k0 < NSEQ; k0 += 64) {
    asm volatile("s_waitcnt vmcnt(0)" ::: "memory");  // own DMA done
    __syncthreads();                                  // everyone's DMA done; prev tile consumed
    if (k0 + 64 < NSEQ) stage(buf ^ 1, k0 + 64);      // prefetch DMA under this tile's compute

    // S~ = K.Q^T  (swapped operands: col=ln16=query, row=quad*4+r=key)
    f32x4 S[4];
    __builtin_amdgcn_s_setprio(1);
#pragma unroll
    for (int nt = 0; nt < 4; ++nt) {
      const unsigned short* kr = &Ks[buf][nt * 16 + ln16][0];
      bf16x8 kb0 = *(const bf16x8*)(kr + (quad ^ sw) * 8);
      bf16x8 kb1 = *(const bf16x8*)(kr + ((quad + 4) ^ sw) * 8);
      f32x4 s = (f32x4){0.f, 0.f, 0.f, 0.f};
      s = __builtin_amdgcn_mfma_f32_16x16x32_bf16(kb0, qf[0], s, 0, 0, 0);
      s = __builtin_amdgcn_mfma_f32_16x16x32_bf16(kb1, qf[1], s, 0, 0, 0);
      S[nt] = s;
    }
    __builtin_amdgcn_s_setprio(0);

    // P = exp2(S~) -> bf16 pack -> in-register quad exchange -> PV A-frags.
    bf16x8 pa[2];
    {
      unsigned int c[4][2];
#pragma unroll
      for (int nt = 0; nt < 4; ++nt) {
        float e0 = exp2_fast(S[nt][0]);
        float e1 = exp2_fast(S[nt][1]);
        float e2 = exp2_fast(S[nt][2]);
        float e3 = exp2_fast(S[nt][3]);
        asm volatile("v_cvt_pk_bf16_f32 %0, %1, %2" : "=v"(c[nt][0]) : "v"(e0), "v"(e1));
        asm volatile("v_cvt_pk_bf16_f32 %0, %1, %2" : "=v"(c[nt][1]) : "v"(e2), "v"(e3));
      }
#pragma unroll
      for (int kh = 0; kh < 2; ++kh) {
        unsigned int a0 = c[2 * kh][0], a1 = c[2 * kh][1];
        unsigned int a2 = c[2 * kh + 1][0], a3 = c[2 * kh + 1][1];
        asm volatile("v_permlane32_swap_b32 %0, %1" : "+v"(a0), "+v"(a2));
        asm volatile("v_permlane16_swap_b32 %0, %1" : "+v"(a0), "+v"(a2));
        asm volatile("v_permlane32_swap_b32 %0, %1" : "+v"(a1), "+v"(a3));
        asm volatile("v_permlane16_swap_b32 %0, %1" : "+v"(a1), "+v"(a3));
        union { unsigned int u[4]; bf16x8 v; } P;
        P.u[0] = a0; P.u[1] = a1; P.u[2] = a2; P.u[3] = a3;
        pa[kh] = P.v;
      }
    }

    // O += P.V (+ ones column accumulates denominator)
    __builtin_amdgcn_s_setprio(1);
#pragma unroll
    for (int nt = 0; nt < 5; ++nt) {
      bf16x8 vb0, vb1;
      if (nt < 4) {
        const unsigned short* vr = &Vts[buf][nt * 16 + ln16][0];
        vb0 = *(const bf16x8*)(vr + (quad ^ sw) * 8);
        vb1 = *(const bf16x8*)(vr + ((quad + 4) ^ sw) * 8);
      } else {
        vb0 = vone; vb1 = vone;
      }
      O[nt] = __builtin_amdgcn_mfma_f32_16x16x32_bf16(pa[0], vb0, O[nt], 0, 0, 0);
      O[nt] = __builtin_amdgcn_mfma_f32_16x16x32_bf16(pa[1], vb1, O[nt], 0, 0, 0);
    }
    __builtin_amdgcn_s_setprio(0);
    buf ^= 1;
  }

  int bb = bh / HEADS, h = bh % HEADS;
#pragma unroll
  for (int r = 0; r < 4; ++r) {
    float lsum = O[4][r];
    lsum = __shfl(lsum, lane & 48);  // broadcast from ln16==0 of this quad
    float inv = 1.f / lsum;
    int token = q0 + wave * 16 + quad * 4 + r;
    unsigned short* op = ctxb + ((size_t)(bb * NSEQ + token)) * DIM + h * DH;
#pragma unroll
    for (int nt = 0; nt < 4; ++nt)
      op[nt * 16 + ln16] = f2bf(O[nt][r] * inv);
  }
}

// ---------------------------------------------------------------------------
extern "C" void kernel_launch(void* const* d_in, const int* in_sizes, int n_in,
                              void* d_out, int out_size, void* d_ws, size_t ws_size,
                              hipStream_t stream) {
  const float* x = (const float*)d_in[0];
  const float* w_qkv = (const float*)d_in[1];
  const float* b_qkv = (const float*)d_in[2];
  const float* w_out = (const float*)d_in[3];
  const float* b_out = (const float*)d_in[4];
  float* out = (float*)d_out;

  const size_t plane = (size_t)BH * NSEQ * DH;  // 6,291,456
  unsigned short* xb = (unsigned short*)d_ws;            // [8192][768]
  unsigned short* wqkvT = xb + plane;                    // [2304][768]
  unsigned short* woutT = wqkvT + (size_t)3 * DIM * DIM; // [768][768]
  unsigned short* Qb = woutT + (size_t)DIM * DIM;        // [bh][n][64]
  unsigned short* Kb = Qb + plane;                       // [bh][n][64]
  unsigned short* Vtb = Kb + plane;                      // [bh][64][n]
  unsigned short* ctxb = Vtb + plane;                    // [8192][768]

  cvt_bf16<<<dim3((int)(plane / 2048)), 256, 0, stream>>>(x, xb, (int)plane);
  transpose_cvt2<<<dim3(96, 24), 256, 0, stream>>>(w_qkv, wqkvT, w_out, woutT);

  // QKV GEMM: V written directly transposed (vtrans fused into epilogue).
  gemm_bt<64><<<dim3(3 * DIM / 128, BATCH * NSEQ / 64), 256, 0, stream>>>(
      xb, wqkvT, b_qkv, nullptr, Qb, Kb, Vtb, BATCH * NSEQ, 3 * DIM, DIM, 0);

  attn_mfma6<<<dim3(NSEQ / 64, BH), 256, 0, stream>>>(Qb, Kb, Vtb, ctxb);

  gemm_bt<64><<<dim3(DIM / 128, BATCH * NSEQ / 64), 256, 0, stream>>>(
      ctxb, woutT, b_out, out, nullptr, nullptr, nullptr, BATCH * NSEQ, DIM, DIM, 1);
}

// Round 11
// 246.193 us; speedup vs baseline: 1.1252x; 1.1252x over previous
//
#include <hip/hip_runtime.h>
#include <math.h>

#define DIM 768
#define HEADS 12
#define DH 64
#define NSEQ 4096
#define BATCH 2
#define BH (BATCH * HEADS)

typedef __attribute__((ext_vector_type(8))) short bf16x8;
typedef __attribute__((ext_vector_type(4))) float f32x4;

typedef const __attribute__((address_space(1))) unsigned char* as1_u8;
typedef __attribute__((address_space(3))) unsigned char* as3_u8;

// round-half-up bf16: <=0.5 ULP, 2 VALU ops
__device__ __forceinline__ unsigned short f2bf(float x) {
  return (unsigned short)((__float_as_uint(x) + 0x8000u) >> 16);
}

// raw v_exp_f32 = 2^x. s_nop 0 covers the trans->VALU 1-wait-state hazard.
__device__ __forceinline__ float exp2_fast(float x) {
  float r;
  asm volatile("v_exp_f32 %0, %1\n\ts_nop 0" : "=v"(r) : "v"(x));
  return r;
}

// async global->LDS DMA, 16B per lane; LDS dest = wave-uniform base + lane*16
__device__ __forceinline__ void gl16(const void* g, void* l) {
  __builtin_amdgcn_global_load_lds((as1_u8)g, (as3_u8)l, 16, 0, 0);
}

// ---------------------------------------------------------------------------
// fp32 -> bf16 elementwise (x). 8 elems/thread. 38 MB traffic (~8 us).
// ---------------------------------------------------------------------------
__global__ __launch_bounds__(256) void cvt_bf16(const float* __restrict__ in,
                                                unsigned short* __restrict__ out,
                                                int n) {
  int i = (blockIdx.x * 256 + threadIdx.x) * 8;
  if (i >= n) return;
  float4 a = *(const float4*)(in + i);
  float4 b = *(const float4*)(in + i + 4);
  ushort4 v0, v1;
  v0.x = f2bf(a.x); v0.y = f2bf(a.y); v0.z = f2bf(a.z); v0.w = f2bf(a.w);
  v1.x = f2bf(b.x); v1.y = f2bf(b.y); v1.z = f2bf(b.z); v1.w = f2bf(b.w);
  *(ushort4*)(out + i) = v0;
  *(ushort4*)(out + i + 4) = v1;
}

// ---------------------------------------------------------------------------
// Merged weight transpose+convert: both w_qkv [768][2304] and w_out [768][768]
// fp32 -> [N][768] bf16 in ONE launch (grid.x 0..71 -> qkv, 72..95 -> out).
// ---------------------------------------------------------------------------
__global__ __launch_bounds__(256) void transpose_cvt2(
    const float* __restrict__ wqkv, unsigned short* __restrict__ wqkvT,
    const float* __restrict__ wout, unsigned short* __restrict__ woutT) {
  __shared__ unsigned short s[32][34];
  int t = threadIdx.x;
  int tx = t & 31, ty = t >> 5;
  int bx = blockIdx.x;
  const float* in;
  unsigned short* out;
  int N, n0;
  if (bx < 72) { in = wqkv; out = wqkvT; N = 3 * DIM; n0 = bx * 32; }
  else         { in = wout; out = woutT; N = DIM;     n0 = (bx - 72) * 32; }
  int k0 = blockIdx.y * 32;
#pragma unroll
  for (int i = 0; i < 4; ++i) {
    int r = ty + i * 8;
    s[r][tx] = f2bf(in[(size_t)(k0 + r) * N + n0 + tx]);
  }
  __syncthreads();
#pragma unroll
  for (int i = 0; i < 4; ++i) {
    int r = ty + i * 8;
    out[(size_t)(n0 + r) * DIM + k0 + tx] = s[tx][r];
  }
}

// ---------------------------------------------------------------------------
// bf16 MFMA GEMM v8: C[M,N] = A[M,K] @ Bt[N,K]^T + bias.
// Double-buffered K-loop (attn-style): {vmcnt(0); barrier; issue next-tile
// DMA into buf^1; MFMA on buf}. One barrier per K-step. TM=64,
// LDS 2x24KB=48KB -> 3 blocks/CU. global_load_lds 16B DMA, content
// XOR-chunk-swizzled via pre-swizzled global source; XCD-aware block swizzle.
// mode 0 (QKV): -> Qb(scaled)/Kb bf16 rows; V blocks (which==2,
// block-uniform) are read back TRANSPOSED from the C-scratch and written
// straight to Vt [bh][dh][n] (vtrans kernel fused away).
// mode 1: fp32 out rows, full-line stores.
// ---------------------------------------------------------------------------
template <int TM>
__global__ __launch_bounds__(256, 3) void gemm_bt(
    const unsigned short* __restrict__ Ab, const unsigned short* __restrict__ Bt,
    const float* __restrict__ bias, float* __restrict__ outf,
    unsigned short* __restrict__ Qb, unsigned short* __restrict__ Kb,
    unsigned short* __restrict__ Vt, int M, int N, int K, int mode) {
  constexpr int ABYTES = TM * 128;   // per-buffer A bytes
  constexpr int BBYTES = 128 * 128;  // per-buffer B bytes
  __shared__ __align__(16) char Sraw[2 * (ABYTES + BBYTES)];
  constexpr int MI = TM / 32;
  const int t = threadIdx.x;
  const int wave = t >> 6, lane = t & 63;
  const int ln16 = lane & 15, quad = lane >> 4;
  const int sw = ln16 & 7;

  // XCD-aware swizzle: each XCD gets a contiguous chunk of work ids.
  const int nbx = gridDim.x;
  const int nwg = nbx * gridDim.y;
  int bid = blockIdx.x + blockIdx.y * nbx;
  int nbid = (bid & 7) * (nwg >> 3) + (bid >> 3);  // nwg % 8 == 0 for both gemms
  const int cb = nbid % nbx, rb = nbid / nbx;

  const int rw = (wave >> 1) * (TM / 2);
  const int cw = (wave & 1) * 64;

  // DMA geometry: one gl16 covers 8 rows x 128B. row8=lane>>3, chunk lane&7.
  // Source chunk pre-swizzled so LDS[row][c] = true[row][c ^ (row&7)].
  const int row8 = lane >> 3;
  const int csw = (lane & 7) ^ row8;

  f32x4 acc[MI][4];
#pragma unroll
  for (int i = 0; i < MI; ++i)
#pragma unroll
    for (int j = 0; j < 4; ++j) acc[i][j] = (f32x4){0.f, 0.f, 0.f, 0.f};

  const unsigned short* gA = Ab + (size_t)(rb * TM + row8) * K + csw * 8;
  const unsigned short* gB = Bt + (size_t)(cb * 128 + row8) * K + csw * 8;

  auto stage = [&](int b, int k0) {
    char* base = Sraw + b * (ABYTES + BBYTES);
    unsigned short* As = (unsigned short*)base;
    unsigned short* Bs = (unsigned short*)(base + ABYTES);
#pragma unroll
    for (int i = 0; i < MI; ++i) {
      int rr = wave * (TM / 4) + i * 8;
      gl16(gA + (size_t)rr * K + k0, &As[rr * 64]);
    }
#pragma unroll
    for (int i = 0; i < 4; ++i) {
      int rr = wave * 32 + i * 8;
      gl16(gB + (size_t)rr * K + k0, &Bs[rr * 64]);
    }
  };

  stage(0, 0);
  int buf = 0;

  for (int k0 = 0; k0 < K; k0 += 64) {
    asm volatile("s_waitcnt vmcnt(0)" ::: "memory");  // own DMA for buf done
    __syncthreads();  // all waves' DMA done; prev tile (buf^1) fully consumed
    if (k0 + 64 < K) stage(buf ^ 1, k0 + 64);  // prefetch rides this compute

    const unsigned short* Asb =
        (const unsigned short*)(Sraw + buf * (ABYTES + BBYTES));
    const unsigned short* Bs =
        (const unsigned short*)(Sraw + buf * (ABYTES + BBYTES) + ABYTES);
#pragma unroll
    for (int kh = 0; kh < 2; ++kh) {
      bf16x8 a[MI], b[4];
#pragma unroll
      for (int mi = 0; mi < MI; ++mi) {
        int row = rw + mi * 16 + ln16;
        a[mi] = *(const bf16x8*)&Asb[row * 64 + (((kh << 2) | quad) ^ sw) * 8];
      }
#pragma unroll
      for (int ni = 0; ni < 4; ++ni) {
        int row = cw + ni * 16 + ln16;
        b[ni] = *(const bf16x8*)&Bs[row * 64 + (((kh << 2) | quad) ^ sw) * 8];
      }
#pragma unroll
      for (int mi = 0; mi < MI; ++mi)
#pragma unroll
        for (int ni = 0; ni < 4; ++ni)
          acc[mi][ni] = __builtin_amdgcn_mfma_f32_16x16x32_bf16(a[mi], b[ni],
                                                                acc[mi][ni], 0, 0, 0);
    }
    buf ^= 1;
  }

  // epilogue lane mapping for full-line stores
  const int erow = lane >> 3;        // 0..7 (row within 8-row group)
  const int ecol = (lane & 7) * 8;   // elem col (8 elems = 16B bf16 / 32B fp32)

  if (mode == 0) {
    __syncthreads();  // all waves done with LDS tiles; reuse as fp32 C-scratch
    // 768^-0.5 * log2(e): attention uses raw v_exp_f32 (2^x), so the log2e
    // factor is folded into the Q scale here. exp2(S*log2e) == exp(S).
    const float scale = 0.0520587731f;
    int col0abs = cb * 128 + cw;                 // multiple of 64
    int which = (col0abs >= 2 * DIM) ? 2 : ((col0abs >= DIM) ? 1 : 0);
    int h = (col0abs - which * DIM) >> 6;        // wave covers one full head
    const float mul = (which == 0) ? scale : 1.f;
    float* Cs = (float*)Sraw + wave * (16 * 68);  // 16 rows x 68 floats per wave
    float bvv[4];
#pragma unroll
    for (int ni = 0; ni < 4; ++ni) bvv[ni] = bias[col0abs + ni * 16 + ln16];
    int bb = (rb * TM) >> 12;  // batch index, uniform over the block's tokens
    size_t planebase = (size_t)(bb * HEADS + h) * NSEQ;

    if (which == 2) {
      // V: read scratch TRANSPOSED (lane = dh), store to Vt[bh][dh][n]
      // in 16-token 32B runs. Fuses the old vtrans kernel away.
#pragma unroll
      for (int mi = 0; mi < MI; ++mi) {
#pragma unroll
        for (int ni = 0; ni < 4; ++ni)
#pragma unroll
          for (int r = 0; r < 4; ++r)
            Cs[(quad * 4 + r) * 68 + ni * 16 + ln16] = acc[mi][ni][r] + bvv[ni];
        __asm__ volatile("s_waitcnt lgkmcnt(0)" ::: "memory");  // wave-local
        int n0 = (rb * TM + rw + mi * 16) & (NSEQ - 1);
        unsigned short tmp[16];
#pragma unroll
        for (int r = 0; r < 16; ++r) tmp[r] = f2bf(Cs[r * 68 + lane]);
        unsigned short* dp =
            Vt + ((size_t)((bb * HEADS + h) * DH + lane)) * NSEQ + n0;
        *(uint4*)&dp[0] = *(uint4*)&tmp[0];
        *(uint4*)&dp[8] = *(uint4*)&tmp[8];
        __asm__ volatile("s_waitcnt lgkmcnt(0)" ::: "memory");
      }
    } else {
      unsigned short* dstp = (which == 0) ? Qb : Kb;
#pragma unroll
      for (int mi = 0; mi < MI; ++mi) {
#pragma unroll
        for (int ni = 0; ni < 4; ++ni)
#pragma unroll
          for (int r = 0; r < 4; ++r)
            Cs[(quad * 4 + r) * 68 + ni * 16 + ln16] = (acc[mi][ni][r] + bvv[ni]) * mul;
        __asm__ volatile("s_waitcnt lgkmcnt(0)" ::: "memory");  // wave-local
#pragma unroll
        for (int i2 = 0; i2 < 2; ++i2) {
          int rloc = i2 * 8 + erow;
          const float* src = &Cs[rloc * 68 + ecol];
          float4 c0 = *(const float4*)(src + 0);
          float4 c1 = *(const float4*)(src + 4);
          unsigned short tmp[8];
          tmp[0] = f2bf(c0.x); tmp[1] = f2bf(c0.y); tmp[2] = f2bf(c0.z); tmp[3] = f2bf(c0.w);
          tmp[4] = f2bf(c1.x); tmp[5] = f2bf(c1.y); tmp[6] = f2bf(c1.z); tmp[7] = f2bf(c1.w);
          int nn = (rb * TM + rw + mi * 16 + rloc) & (NSEQ - 1);
          // lanes: 8 consecutive rows x 128B contiguous -> 8 full lines/store
          *(uint4*)&dstp[(planebase + nn) * DH + ecol] = *(uint4*)tmp;
        }
        __asm__ volatile("s_waitcnt lgkmcnt(0)" ::: "memory");  // reads done
      }
    }
  } else {
    // mode 1: fp32 out via LDS scratch, full-line stores (each instruction:
    // 8 rows x 128B-contiguous aligned pieces).
    __syncthreads();
    float* Cs = (float*)Sraw + wave * (16 * 68);
    float bvv[4];
#pragma unroll
    for (int ni = 0; ni < 4; ++ni) bvv[ni] = bias[cb * 128 + cw + ni * 16 + ln16];
    const int fcol = (lane & 7) * 4;  // float col within 64, 16B chunks
#pragma unroll
    for (int mi = 0; mi < MI; ++mi) {
#pragma unroll
      for (int ni = 0; ni < 4; ++ni)
#pragma unroll
        for (int r = 0; r < 4; ++r)
          Cs[(quad * 4 + r) * 68 + ni * 16 + ln16] = acc[mi][ni][r] + bvv[ni];
      __asm__ volatile("s_waitcnt lgkmcnt(0)" ::: "memory");  // wave-local
#pragma unroll
      for (int i2 = 0; i2 < 2; ++i2) {
#pragma unroll
        for (int s = 0; s < 2; ++s) {
          int rloc = i2 * 8 + erow;
          int cloc = fcol + s * 32;
          float4 c = *(const float4*)&Cs[rloc * 68 + cloc];
          int token = rb * TM + rw + mi * 16 + rloc;
          *(float4*)(outf + (size_t)token * N + cb * 128 + cw + cloc) = c;
        }
      }
      __asm__ volatile("s_waitcnt lgkmcnt(0)" ::: "memory");
    }
  }
}

// ---------------------------------------------------------------------------
// MFMA flash attention v4 (best measured: 118.6us, 868 TF):
// swapped QK^T + in-register P exchange (cvt_pk_bf16 + permlane swaps),
// global_load_lds double-buffered staging (1 barrier/tile), register
// ones-fragment denominator, exp2 with log2e folded into Q scale upstream,
// XCD-aware block swizzle (3 heads' K/V per XCD -> fits 4MB L2).
// QBLK=128: round-10 ablation showed QBLK=64 regresses (per-tile fixed
// costs constant while compute halves -> MfmaUtil 41->35).
// ---------------------------------------------------------------------------
__global__ __launch_bounds__(256, 3) void attn_mfma4(
    const unsigned short* __restrict__ Qg, const unsigned short* __restrict__ Kg,
    const unsigned short* __restrict__ Vtg, unsigned short* __restrict__ ctxb) {
  __shared__ unsigned short Ks[2][64][64];   // [buf][key][dh], chunk-XOR-swizzled
  __shared__ unsigned short Vts[2][64][64];  // [buf][dh][key], chunk-XOR-swizzled

  const int t = threadIdx.x;
  const int wave = t >> 6, lane = t & 63;
  const int ln16 = lane & 15, quad = lane >> 4;

  // XCD swizzle: nwg = 32*24 = 768, 96 per XCD = 3 heads x 32 q-blocks.
  int bid = blockIdx.x + blockIdx.y * 32;
  int nbid = (bid & 7) * 96 + (bid >> 3);
  const int bh = nbid >> 5;
  const int q0 = (nbid & 31) * 128;

  // Q fragments (registers, whole kernel)
  const unsigned short* Qp = Qg + ((size_t)bh * NSEQ + q0 + wave * 32) * DH;
  bf16x8 qf[2][2];
#pragma unroll
  for (int mi = 0; mi < 2; ++mi)
#pragma unroll
    for (int kh = 0; kh < 2; ++kh)
      qf[mi][kh] = *(const bf16x8*)(Qp + (size_t)(mi * 16 + ln16) * DH + kh * 32 + quad * 8);

  f32x4 O[2][5];
#pragma unroll
  for (int mi = 0; mi < 2; ++mi)
#pragma unroll
    for (int nt = 0; nt < 5; ++nt) O[mi][nt] = (f32x4){0.f, 0.f, 0.f, 0.f};

  const unsigned short* Kbase = Kg + (size_t)bh * NSEQ * DH;
  const unsigned short* Vbase = Vtg + (size_t)bh * DH * NSEQ;

  // staging geometry: per gl16 a wave covers 8 rows x 128B; row = lane>>3,
  // chunk = lane&7. Source chunk pre-swizzled by row&7 so that
  // LDS[row][c] = true[row][c ^ (row&7)] (16B-chunk XOR swizzle).
  const int row8 = lane >> 3;
  const int csw = (lane & 7) ^ row8;

  auto stage = [&](int b, int kk) {
#pragma unroll
    for (int i = 0; i < 2; ++i) {
      int rr = wave * 16 + i * 8;
      gl16(Kbase + (size_t)(kk + rr + row8) * DH + csw * 8, &Ks[b][rr][0]);
      gl16(Vbase + (size_t)(rr + row8) * NSEQ + kk + csw * 8, &Vts[b][rr][0]);
    }
  };

  // ones B-fragment for denominator column (row 0 of B = ones)
  union { unsigned int u[4]; bf16x8 v; } VO;
  {
    unsigned int ow = (ln16 == 0) ? 0x3F803F80u : 0u;
    VO.u[0] = ow; VO.u[1] = ow; VO.u[2] = ow; VO.u[3] = ow;
  }
  const bf16x8 vone = VO.v;

  stage(0, 0);
  const int sw = ln16 & 7;
  int buf = 0;

  for (int k0 = 0; k0 < NSEQ; k0 += 64) {
    asm volatile("s_waitcnt vmcnt(0)" ::: "memory");  // own DMA done
    __syncthreads();                                  // everyone's DMA done; prev tile consumed
    if (k0 + 64 < NSEQ) stage(buf ^ 1, k0 + 64);      // prefetch DMA under this tile's compute

    // S~ = K.Q^T  (swapped operands: col=ln16=query, row=quad*4+r=key)
    f32x4 S[2][4];
    __builtin_amdgcn_s_setprio(1);
#pragma unroll
    for (int nt = 0; nt < 4; ++nt) {
      const unsigned short* kr = &Ks[buf][nt * 16 + ln16][0];
      bf16x8 kb0 = *(const bf16x8*)(kr + (quad ^ sw) * 8);
      bf16x8 kb1 = *(const bf16x8*)(kr + ((quad + 4) ^ sw) * 8);
#pragma unroll
      for (int mi = 0; mi < 2; ++mi) {
        f32x4 s = (f32x4){0.f, 0.f, 0.f, 0.f};
        s = __builtin_amdgcn_mfma_f32_16x16x32_bf16(kb0, qf[mi][0], s, 0, 0, 0);
        s = __builtin_amdgcn_mfma_f32_16x16x32_bf16(kb1, qf[mi][1], s, 0, 0, 0);
        S[mi][nt] = s;
      }
    }
    __builtin_amdgcn_s_setprio(0);

    // P = exp2(S~) -> bf16 pack -> in-register quad exchange -> PV A-frags.
    bf16x8 pa[2][2];
#pragma unroll
    for (int mi = 0; mi < 2; ++mi) {
      unsigned int c[4][2];
#pragma unroll
      for (int nt = 0; nt < 4; ++nt) {
        float e0 = exp2_fast(S[mi][nt][0]);
        float e1 = exp2_fast(S[mi][nt][1]);
        float e2 = exp2_fast(S[mi][nt][2]);
        float e3 = exp2_fast(S[mi][nt][3]);
        asm volatile("v_cvt_pk_bf16_f32 %0, %1, %2" : "=v"(c[nt][0]) : "v"(e0), "v"(e1));
        asm volatile("v_cvt_pk_bf16_f32 %0, %1, %2" : "=v"(c[nt][1]) : "v"(e2), "v"(e3));
      }
#pragma unroll
      for (int kh = 0; kh < 2; ++kh) {
        unsigned int a0 = c[2 * kh][0], a1 = c[2 * kh][1];
        unsigned int a2 = c[2 * kh + 1][0], a3 = c[2 * kh + 1][1];
        asm volatile("v_permlane32_swap_b32 %0, %1" : "+v"(a0), "+v"(a2));
        asm volatile("v_permlane16_swap_b32 %0, %1" : "+v"(a0), "+v"(a2));
        asm volatile("v_permlane32_swap_b32 %0, %1" : "+v"(a1), "+v"(a3));
        asm volatile("v_permlane16_swap_b32 %0, %1" : "+v"(a1), "+v"(a3));
        union { unsigned int u[4]; bf16x8 v; } P;
        P.u[0] = a0; P.u[1] = a1; P.u[2] = a2; P.u[3] = a3;
        pa[mi][kh] = P.v;
      }
    }

    // O += P.V (+ ones column accumulates denominator)
    __builtin_amdgcn_s_setprio(1);
#pragma unroll
    for (int nt = 0; nt < 5; ++nt) {
      bf16x8 vb0, vb1;
      if (nt < 4) {
        const unsigned short* vr = &Vts[buf][nt * 16 + ln16][0];
        vb0 = *(const bf16x8*)(vr + (quad ^ sw) * 8);
        vb1 = *(const bf16x8*)(vr + ((quad + 4) ^ sw) * 8);
      } else {
        vb0 = vone; vb1 = vone;
      }
#pragma unroll
      for (int mi = 0; mi < 2; ++mi) {
        O[mi][nt] = __builtin_amdgcn_mfma_f32_16x16x32_bf16(pa[mi][0], vb0, O[mi][nt], 0, 0, 0);
        O[mi][nt] = __builtin_amdgcn_mfma_f32_16x16x32_bf16(pa[mi][1], vb1, O[mi][nt], 0, 0, 0);
      }
    }
    __builtin_amdgcn_s_setprio(0);
    buf ^= 1;
  }

  int bb = bh / HEADS, h = bh % HEADS;
#pragma unroll
  for (int mi = 0; mi < 2; ++mi)
#pragma unroll
    for (int r = 0; r < 4; ++r) {
      float lsum = O[mi][4][r];
      lsum = __shfl(lsum, lane & 48);  // broadcast from ln16==0 of this quad
      float inv = 1.f / lsum;
      int token = q0 + wave * 32 + mi * 16 + quad * 4 + r;
      unsigned short* op = ctxb + ((size_t)(bb * NSEQ + token)) * DIM + h * DH;
#pragma unroll
      for (int nt = 0; nt < 4; ++nt)
        op[nt * 16 + ln16] = f2bf(O[mi][nt][r] * inv);
    }
}

// ---------------------------------------------------------------------------
extern "C" void kernel_launch(void* const* d_in, const int* in_sizes, int n_in,
                              void* d_out, int out_size, void* d_ws, size_t ws_size,
                              hipStream_t stream) {
  const float* x = (const float*)d_in[0];
  const float* w_qkv = (const float*)d_in[1];
  const float* b_qkv = (const float*)d_in[2];
  const float* w_out = (const float*)d_in[3];
  const float* b_out = (const float*)d_in[4];
  float* out = (float*)d_out;

  const size_t plane = (size_t)BH * NSEQ * DH;  // 6,291,456
  unsigned short* xb = (unsigned short*)d_ws;            // [8192][768]
  unsigned short* wqkvT = xb + plane;                    // [2304][768]
  unsigned short* woutT = wqkvT + (size_t)3 * DIM * DIM; // [768][768]
  unsigned short* Qb = woutT + (size_t)DIM * DIM;        // [bh][n][64]
  unsigned short* Kb = Qb + plane;                       // [bh][n][64]
  unsigned short* Vtb = Kb + plane;                      // [bh][64][n]
  unsigned short* ctxb = Vtb + plane;                    // [8192][768]

  cvt_bf16<<<dim3((int)(plane / 2048)), 256, 0, stream>>>(x, xb, (int)plane);
  transpose_cvt2<<<dim3(96, 24), 256, 0, stream>>>(w_qkv, wqkvT, w_out, woutT);

  // QKV GEMM: V written directly transposed (vtrans fused into epilogue).
  gemm_bt<64><<<dim3(3 * DIM / 128, BATCH * NSEQ / 64), 256, 0, stream>>>(
      xb, wqkvT, b_qkv, nullptr, Qb, Kb, Vtb, BATCH * NSEQ, 3 * DIM, DIM, 0);

  attn_mfma4<<<dim3(NSEQ / 128, BH), 256, 0, stream>>>(Qb, Kb, Vtb, ctxb);

  gemm_bt<64><<<dim3(DIM / 128, BATCH * NSEQ / 64), 256, 0, stream>>>(
      ctxb, woutT, b_out, out, nullptr, nullptr, nullptr, BATCH * NSEQ, DIM, DIM, 1);
}